// Round 4
// baseline (514.433 us; speedup 1.0000x reference)
//
#include <hip/hip_runtime.h>
#include <hip/hip_cooperative_groups.h>
#include <cmath>

namespace cg = cooperative_groups;

// HistorySAGE: 3 GraphSAGE layers. Only rows < 20000 of any intermediate are
// ever consumed (idx < NN0=20000, output rows < 20000), so each layer computes
// exactly 20000 rows. Preferred path: ONE cooperative kernel with grid.sync();
// fallback (if cooperative launch is rejected): 4 plain launches.
constexpr int ROWS = 20000;
constexpr int BM   = 32;            // rows per block tile
constexpr int GRID = ROWS / BM;     // 625 blocks; 3 blocks/CU co-resident by construction
constexpr float BN_EPS = 1e-5f;

using f32x4  = __attribute__((ext_vector_type(4))) float;
using short8 = __attribute__((ext_vector_type(8))) short;

__device__ __forceinline__ float bf2f(unsigned short u) {
    unsigned int x = ((unsigned int)u) << 16;
    return __builtin_bit_cast(float, x);
}
__device__ __forceinline__ unsigned short f2bf(float f) {
    unsigned int x = __builtin_bit_cast(unsigned int, f);
    unsigned int r = x + 0x7fffu + ((x >> 16) & 1u);   // RNE
    return (unsigned short)(r >> 16);
}

struct Args {
    const float* x; const int* ptr; const int* idx;
    const float *W0, *b0, *R0, *W1, *b1, *R1, *W2, *b2, *R2;
    const float *g0, *be0, *rm0, *rv0, *g1, *be1, *rm1, *rv1;
    unsigned short *B0, *B1, *B2, *h0, *h1;
    float* out;
};

// Bcat[n][kk] bf16: kk<K -> W[kk][n], else R[kk-K][n]; n>=Ntrue -> 0.
__device__ __forceinline__ void convw(const float* W, const float* R, unsigned short* B,
                                      int K, int Ntrue, int Npad, int gtid, int gstride)
{
    const int Kt = 2 * K;
    for (int e = gtid; e < Npad * Kt; e += gstride) {
        const int n = e / Kt, kk = e - n * Kt;
        float v = 0.f;
        if (n < Ntrue) v = (kk < K) ? W[(size_t)kk * Ntrue + n] : R[(size_t)(kk - K) * Ntrue + n];
        B[e] = f2bf(v);
    }
}

// Stage per-tile graph meta (ptr/idx identical across all 3 layers).
__device__ __forceinline__ void stage_meta(const int* __restrict__ ptr, const int* __restrict__ idx,
    int rowBase, int* sOff, int* sCnt, float* sInv, int* sIdx, int tid)
{
    if (tid < BM) {
        const int p0 = ptr[rowBase + tid], p1 = ptr[rowBase + tid + 1];
        sOff[tid] = p0; sCnt[tid] = p1 - p0; sInv[tid] = 1.0f / (float)(p1 - p0);
    }
    __syncthreads();
    for (int u = tid; u < BM * 10; u += 256) {       // BUGFIX: strided loop (320 > 256 threads)
        const int r = u / 10, j = u - r * 10;
        sIdx[u] = (j < sCnt[r]) ? idx[sOff[r] + j] : 0;
    }
    __syncthreads();
}

// Stage [agg(10-nb mean) | self] rows as bf16 into sA[BM][2K+8].
template<int K, bool SRC_BF16>
__device__ __forceinline__ void stage_rows(const float* srcF, const unsigned short* srcB,
    const int* __restrict__ gidx, const int* sIdx, const int* sOff, const int* sCnt,
    const float* sInv, int rowBase, unsigned short* sA, int tid)
{
    constexpr int Kt = 2 * K, KP = Kt + 8, CA = K / 8;
    for (int u = tid; u < BM * CA; u += 256) {
        const int r = u / CA, c = (u - (u / CA) * CA) * 8;
        const int row = rowBase + r;
        const int cnt = sCnt[r];
        float acc[8];
        #pragma unroll
        for (int q = 0; q < 8; ++q) acc[q] = 0.f;

        if (__builtin_expect(cnt == 10, 1)) {
            int nb[10];
            #pragma unroll
            for (int j = 0; j < 10; ++j) nb[j] = sIdx[r * 10 + j];
            if constexpr (SRC_BF16) {
                short8 v[10];
                #pragma unroll
                for (int j = 0; j < 10; ++j) v[j] = *(const short8*)(srcB + (size_t)nb[j] * K + c);
                #pragma unroll
                for (int j = 0; j < 10; ++j)
                    #pragma unroll
                    for (int q = 0; q < 8; ++q) acc[q] += bf2f((unsigned short)v[j][q]);
            } else {
                float4 v[10];
                #pragma unroll
                for (int j = 0; j < 10; ++j) v[j] = *(const float4*)(srcF + (size_t)nb[j] * K + c);
                #pragma unroll
                for (int j = 0; j < 10; ++j) { acc[0]+=v[j].x; acc[1]+=v[j].y; acc[2]+=v[j].z; acc[3]+=v[j].w; }
                #pragma unroll
                for (int j = 0; j < 10; ++j) v[j] = *(const float4*)(srcF + (size_t)nb[j] * K + c + 4);
                #pragma unroll
                for (int j = 0; j < 10; ++j) { acc[4]+=v[j].x; acc[5]+=v[j].y; acc[6]+=v[j].z; acc[7]+=v[j].w; }
            }
        } else {
            for (int p = 0; p < cnt; ++p) {
                const int nb = gidx[sOff[r] + p];
                if constexpr (SRC_BF16) {
                    const short8 v = *(const short8*)(srcB + (size_t)nb * K + c);
                    #pragma unroll
                    for (int q = 0; q < 8; ++q) acc[q] += bf2f((unsigned short)v[q]);
                } else {
                    const float4 v0 = *(const float4*)(srcF + (size_t)nb * K + c);
                    const float4 v1 = *(const float4*)(srcF + (size_t)nb * K + c + 4);
                    acc[0]+=v0.x; acc[1]+=v0.y; acc[2]+=v0.z; acc[3]+=v0.w;
                    acc[4]+=v1.x; acc[5]+=v1.y; acc[6]+=v1.z; acc[7]+=v1.w;
                }
            }
        }
        const float inv = sInv[r];
        short8 o;
        #pragma unroll
        for (int q = 0; q < 8; ++q) o[q] = (short)f2bf(acc[q] * inv);
        *(short8*)(&sA[r * KP + c]) = o;

        short8 xs;
        if constexpr (SRC_BF16) {
            xs = *(const short8*)(srcB + (size_t)row * K + c);
        } else {
            const float4 v0 = *(const float4*)(srcF + (size_t)row * K + c);
            const float4 v1 = *(const float4*)(srcF + (size_t)row * K + c + 4);
            xs[0]=(short)f2bf(v0.x); xs[1]=(short)f2bf(v0.y); xs[2]=(short)f2bf(v0.z); xs[3]=(short)f2bf(v0.w);
            xs[4]=(short)f2bf(v1.x); xs[5]=(short)f2bf(v1.y); xs[6]=(short)f2bf(v1.z); xs[7]=(short)f2bf(v1.w);
        }
        *(short8*)(&sA[r * KP + K + c]) = xs;
    }
}

// 32 rows x 256 cols: 4 waves x (2 row-tiles x 4 col-tiles), BN+ReLU -> bf16.
template<int Kt>
__device__ __forceinline__ void gemm256(const unsigned short* sA, const unsigned short* __restrict__ Bcat,
    const float* bias, const float* gam, const float* bet, const float* rmean, const float* rvar,
    unsigned short* __restrict__ dst, int rowBase, int tid)
{
    constexpr int KP = Kt + 8;
    const int lane = tid & 63, wid = tid >> 6;
    const int mrow = lane & 15, kg = (lane >> 4) * 8;
    f32x4 acc[2][4];
    #pragma unroll
    for (int a = 0; a < 2; ++a)
        #pragma unroll
        for (int t = 0; t < 4; ++t) acc[a][t] = (f32x4){0.f, 0.f, 0.f, 0.f};
    const int ncol0 = wid * 64;
    #pragma unroll
    for (int k0 = 0; k0 < Kt; k0 += 32) {
        const short8 a0 = *(const short8*)(&sA[mrow * KP + k0 + kg]);
        const short8 a1 = *(const short8*)(&sA[(16 + mrow) * KP + k0 + kg]);
        #pragma unroll
        for (int t = 0; t < 4; ++t) {
            const short8 b = *(const short8*)(Bcat + (size_t)(ncol0 + t * 16 + mrow) * Kt + k0 + kg);
            acc[0][t] = __builtin_amdgcn_mfma_f32_16x16x32_bf16(a0, b, acc[0][t], 0, 0, 0);
            acc[1][t] = __builtin_amdgcn_mfma_f32_16x16x32_bf16(a1, b, acc[1][t], 0, 0, 0);
        }
    }
    #pragma unroll
    for (int t = 0; t < 4; ++t) {
        const int col = ncol0 + t * 16 + mrow;
        const float sc = gam[col] * rsqrtf(rvar[col] + BN_EPS);
        const float sh = bet[col] - rmean[col] * sc;
        const float bb = bias[col];
        #pragma unroll
        for (int a = 0; a < 2; ++a)
            #pragma unroll
            for (int reg = 0; reg < 4; ++reg) {
                const int row = rowBase + a * 16 + (lane >> 4) * 4 + reg;
                float h = acc[a][t][reg] + bb;
                h = fmaxf(h * sc + sh, 0.f);
                dst[(size_t)row * 256 + col] = f2bf(h);
            }
    }
}

// 32 rows x 47 cols: waves 0,1 each 16 rows x 3 col-tiles, log_softmax -> f32.
template<int Kt>
__device__ __forceinline__ void gemm48(const unsigned short* sA, const unsigned short* __restrict__ Bcat,
    const float* bias, float* __restrict__ out, int rowBase, int tid)
{
    constexpr int KP = Kt + 8;
    const int lane = tid & 63, wid = tid >> 6;
    if (wid >= 2) return;                       // last phase: no further barriers
    const int mrow = lane & 15, kg = (lane >> 4) * 8;
    f32x4 acc[3];
    #pragma unroll
    for (int t = 0; t < 3; ++t) acc[t] = (f32x4){0.f, 0.f, 0.f, 0.f};
    #pragma unroll
    for (int k0 = 0; k0 < Kt; k0 += 32) {
        const short8 a = *(const short8*)(&sA[(wid * 16 + mrow) * KP + k0 + kg]);
        #pragma unroll
        for (int t = 0; t < 3; ++t) {
            const short8 b = *(const short8*)(Bcat + (size_t)(t * 16 + mrow) * Kt + k0 + kg);
            acc[t] = __builtin_amdgcn_mfma_f32_16x16x32_bf16(a, b, acc[t], 0, 0, 0);
        }
    }
    const int c0 = mrow, c1 = 16 + mrow, c2 = 32 + mrow;
    const float bb0 = bias[c0], bb1 = bias[c1];
    const float bb2 = (c2 < 47) ? bias[c2] : 0.f;
    #pragma unroll
    for (int reg = 0; reg < 4; ++reg) {
        const int grow = rowBase + wid * 16 + (lane >> 4) * 4 + reg;
        const float v0 = acc[0][reg] + bb0;
        const float v1 = acc[1][reg] + bb1;
        const float v2 = (c2 < 47) ? acc[2][reg] + bb2 : -3.0e38f;
        float mx = fmaxf(fmaxf(v0, v1), v2);
        #pragma unroll
        for (int o = 1; o < 16; o <<= 1) mx = fmaxf(mx, __shfl_xor(mx, o, 16));
        float s = expf(v0 - mx) + expf(v1 - mx) + ((c2 < 47) ? expf(v2 - mx) : 0.f);
        #pragma unroll
        for (int o = 1; o < 16; o <<= 1) s += __shfl_xor(s, o, 16);
        const float ls = mx + logf(s);
        out[(size_t)grow * 47 + c0] = v0 - ls;
        out[(size_t)grow * 47 + c1] = v1 - ls;
        if (c2 < 47) out[(size_t)grow * 47 + c2] = v2 - ls;
    }
}

// ---- preferred: single cooperative kernel ----
__global__ __launch_bounds__(256, 3) void fused(Args a)
{
    __shared__ unsigned short sA[BM * 520];   // max KP = 2*256+8
    __shared__ int   sIdx[BM * 10];
    __shared__ int   sOff[BM];
    __shared__ int   sCnt[BM];
    __shared__ float sInv[BM];

    const int tid = threadIdx.x, bid = blockIdx.x;
    const int rowBase = bid * BM;
    const int gtid = bid * 256 + tid, gstride = GRID * 256;
    cg::grid_group grid = cg::this_grid();

    stage_meta(a.ptr, a.idx, rowBase, sOff, sCnt, sInv, sIdx, tid);

    convw(a.W0, a.R0, a.B0, 128, 256, 256, gtid, gstride);
    convw(a.W1, a.R1, a.B1, 256, 256, 256, gtid, gstride);
    convw(a.W2, a.R2, a.B2, 256,  47,  48, gtid, gstride);
    __threadfence();
    grid.sync();

    stage_rows<128, false>(a.x, nullptr, a.idx, sIdx, sOff, sCnt, sInv, rowBase, sA, tid);
    __syncthreads();
    gemm256<256>(sA, a.B0, a.b0, a.g0, a.be0, a.rm0, a.rv0, a.h0, rowBase, tid);
    __threadfence();
    grid.sync();

    stage_rows<256, true>(nullptr, a.h0, a.idx, sIdx, sOff, sCnt, sInv, rowBase, sA, tid);
    __syncthreads();
    gemm256<512>(sA, a.B1, a.b1, a.g1, a.be1, a.rm1, a.rv1, a.h1, rowBase, tid);
    __threadfence();
    grid.sync();

    stage_rows<256, true>(nullptr, a.h1, a.idx, sIdx, sOff, sCnt, sInv, rowBase, sA, tid);
    __syncthreads();
    gemm48<512>(sA, a.B2, a.b2, a.out, rowBase, tid);
}

// ---- fallback: plain launches ----
__global__ __launch_bounds__(256) void convw_all(Args a)
{
    const int gtid = blockIdx.x * 256 + threadIdx.x, gstride = gridDim.x * 256;
    convw(a.W0, a.R0, a.B0, 128, 256, 256, gtid, gstride);
    convw(a.W1, a.R1, a.B1, 256, 256, 256, gtid, gstride);
    convw(a.W2, a.R2, a.B2, 256,  47,  48, gtid, gstride);
}

template<int LAYER>
__global__ __launch_bounds__(256) void layer_kernel(Args a)
{
    __shared__ unsigned short sA[BM * 520];
    __shared__ int   sIdx[BM * 10];
    __shared__ int   sOff[BM];
    __shared__ int   sCnt[BM];
    __shared__ float sInv[BM];
    const int tid = threadIdx.x;
    const int rowBase = blockIdx.x * BM;

    stage_meta(a.ptr, a.idx, rowBase, sOff, sCnt, sInv, sIdx, tid);
    if constexpr (LAYER == 0) {
        stage_rows<128, false>(a.x, nullptr, a.idx, sIdx, sOff, sCnt, sInv, rowBase, sA, tid);
        __syncthreads();
        gemm256<256>(sA, a.B0, a.b0, a.g0, a.be0, a.rm0, a.rv0, a.h0, rowBase, tid);
    } else if constexpr (LAYER == 1) {
        stage_rows<256, true>(nullptr, a.h0, a.idx, sIdx, sOff, sCnt, sInv, rowBase, sA, tid);
        __syncthreads();
        gemm256<512>(sA, a.B1, a.b1, a.g1, a.be1, a.rm1, a.rv1, a.h1, rowBase, tid);
    } else {
        stage_rows<256, true>(nullptr, a.h1, a.idx, sIdx, sOff, sCnt, sInv, rowBase, sA, tid);
        __syncthreads();
        gemm48<512>(sA, a.B2, a.b2, a.out, rowBase, tid);
    }
}

extern "C" void kernel_launch(void* const* d_in, const int* in_sizes, int n_in,
                              void* d_out, int out_size, void* d_ws, size_t ws_size,
                              hipStream_t stream)
{
    char* ws = (char*)d_ws;
    Args a;
    a.x   = (const float*)d_in[0];
    a.ptr = (const int*)d_in[1];
    a.idx = (const int*)d_in[2];
    a.W0  = (const float*)d_in[3];  a.b0 = (const float*)d_in[4];  a.R0 = (const float*)d_in[5];
    a.W1  = (const float*)d_in[6];  a.b1 = (const float*)d_in[7];  a.R1 = (const float*)d_in[8];
    a.W2  = (const float*)d_in[9];  a.b2 = (const float*)d_in[10]; a.R2 = (const float*)d_in[11];
    a.g0  = (const float*)d_in[12]; a.be0 = (const float*)d_in[13];
    a.rm0 = (const float*)d_in[14]; a.rv0 = (const float*)d_in[15];
    a.g1  = (const float*)d_in[16]; a.be1 = (const float*)d_in[17];
    a.rm1 = (const float*)d_in[18]; a.rv1 = (const float*)d_in[19];
    a.B0  = (unsigned short*)(ws);                       // 256*256 bf16 = 128 KB
    a.B1  = (unsigned short*)(ws + 131072);              // 256*512 bf16 = 256 KB
    a.B2  = (unsigned short*)(ws + 393216);              //  48*512 bf16 =  48 KB
    a.h0  = (unsigned short*)(ws + 442368);              // 20000*256 bf16
    a.h1  = (unsigned short*)(ws + 442368 + 10240000);   // 20000*256 bf16
    a.out = (float*)d_out;

    void* params[] = { (void*)&a };
    hipError_t err = hipLaunchCooperativeKernel((const void*)fused, dim3(GRID), dim3(256),
                                                params, 0, stream);
    if (err != hipSuccess) {
        // cooperative launch rejected (e.g. under graph capture) -> plain path
        convw_all<<<120, 256, 0, stream>>>(a);
        layer_kernel<0><<<GRID, 256, 0, stream>>>(a);
        layer_kernel<1><<<GRID, 256, 0, stream>>>(a);
        layer_kernel<2><<<GRID, 256, 0, stream>>>(a);
    }
}

// Round 5
// 82.719 us; speedup vs baseline: 6.2191x; 6.2191x over previous
//
#include <hip/hip_runtime.h>
#include <cmath>

// HistorySAGE: 3 GraphSAGE layers, each computing only the 20000 live rows
// (idx < 20000, output rows < 20000). Multi-launch (graph-replayed) structure:
// coop grid.sync measured 3.2x SLOWER on MI355X (round 4: 513us, all pipes idle).
// Round 5: 4 launches, BM=64, bf16 x, fragment-major coalesced weight layout.
constexpr int ROWS = 20000;
constexpr int RPAD = 20032;          // padded to BM multiple; buffers sized RPAD
constexpr int BM   = 64;             // rows per block tile
constexpr int GRID = RPAD / BM;      // 313 blocks
constexpr float BN_EPS = 1e-5f;

using f32x4  = __attribute__((ext_vector_type(4))) float;
using short8 = __attribute__((ext_vector_type(8))) short;

__device__ __forceinline__ float bf2f(unsigned short u) {
    unsigned int x = ((unsigned int)u) << 16;
    return __builtin_bit_cast(float, x);
}
__device__ __forceinline__ unsigned short f2bf(float f) {
    unsigned int x = __builtin_bit_cast(unsigned int, f);
    unsigned int r = x + 0x7fffu + ((x >> 16) & 1u);   // RNE
    return (unsigned short)(r >> 16);
}

// Fragment-major weight layout: Bf[((n16*K32 + k32)*64 + lane)*8 + q] =
// bf16 of Wcat[k32*32 + (lane>>4)*8 + q][n16*16 + (lane&15)], where
// Wcat = [W; R] (2K x N). A wave reading lane*8 shorts at a (n16,k32) block
// base gets its exact 16x16x32 MFMA B-fragment fully coalesced (1KB/wave).
__device__ __forceinline__ void convw_frag(const float* __restrict__ W, const float* __restrict__ R,
                                           unsigned short* __restrict__ B, int K, int Ntrue, int N16,
                                           int gtid, int gstride)
{
    const int K32 = 2 * K / 32;
    const int total = N16 * K32 * 64;
    for (int j = gtid; j < total; j += gstride) {
        const int lane = j & 63;
        const int rest = j >> 6;
        const int k32 = rest % K32, n16 = rest / K32;
        const int n  = n16 * 16 + (lane & 15);
        const int kb = k32 * 32 + (lane >> 4) * 8;
        short8 o;
        #pragma unroll
        for (int q = 0; q < 8; ++q) {
            const int kk = kb + q;
            float v = 0.f;
            if (n < Ntrue) v = (kk < K) ? W[(size_t)kk * Ntrue + n] : R[(size_t)(kk - K) * Ntrue + n];
            o[q] = (short)f2bf(v);
        }
        *(short8*)(B + (size_t)j * 8) = o;
    }
}

struct Args {
    const float* x; const int* ptr; const int* idx;
    const float *W0, *b0, *R0, *W1, *b1, *R1, *W2, *b2, *R2;
    const float *g0, *be0, *rm0, *rv0, *g1, *be1, *rm1, *rv1;
    unsigned short *B0, *B1, *B2, *xb, *h0, *h1;
    float* out;
};

// prep: x rows [0,RPAD) -> bf16 (halves L0 gather bytes) + all weight buffers.
__global__ __launch_bounds__(256) void prep(Args a)
{
    const int gtid = blockIdx.x * 256 + threadIdx.x, gstride = gridDim.x * 256;
    for (int i = gtid; i < RPAD * 16; i += gstride) {
        const int row = i >> 4, c = (i & 15) * 8;
        const float4 v0 = *(const float4*)(a.x + (size_t)row * 128 + c);
        const float4 v1 = *(const float4*)(a.x + (size_t)row * 128 + c + 4);
        short8 o;
        o[0]=(short)f2bf(v0.x); o[1]=(short)f2bf(v0.y); o[2]=(short)f2bf(v0.z); o[3]=(short)f2bf(v0.w);
        o[4]=(short)f2bf(v1.x); o[5]=(short)f2bf(v1.y); o[6]=(short)f2bf(v1.z); o[7]=(short)f2bf(v1.w);
        *(short8*)(a.xb + (size_t)row * 128 + c) = o;
    }
    convw_frag(a.W0, a.R0, a.B0, 128, 256, 16, gtid, gstride);
    convw_frag(a.W1, a.R1, a.B1, 256, 256, 16, gtid, gstride);
    convw_frag(a.W2, a.R2, a.B2, 256,  47,  3, gtid, gstride);
}

// MODE 0: 64 rows x 256 cols, 4 waves x (4 row-frags x 4 col-frags), BN+ReLU -> bf16.
// MODE 1: 64 rows x 47 cols, 4 waves x (1 row-frag x 3 col-frags), log_softmax -> f32.
template<int K, int MODE>
__global__ __launch_bounds__(256, 2)
void layer_kernel(const unsigned short* __restrict__ src,
                  const int* __restrict__ ptr, const int* __restrict__ idx,
                  const unsigned short* __restrict__ Bf, const float* __restrict__ bias,
                  const float* __restrict__ gam, const float* __restrict__ bet,
                  const float* __restrict__ rmean, const float* __restrict__ rvar,
                  unsigned short* __restrict__ dstB, float* __restrict__ dstF)
{
    constexpr int Kt = 2 * K, KP = Kt + 8, CA = K / 8, K32 = Kt / 32;
    __shared__ unsigned short sA[BM * KP];
    __shared__ int   sIdx[BM * 10];
    __shared__ int   sOff[BM];
    __shared__ int   sCnt[BM];
    __shared__ float sInv[BM];

    const int tid = threadIdx.x;
    const int rowBase = blockIdx.x * BM;

    // ---- graph meta ----
    if (tid < BM) {
        const int p0 = ptr[rowBase + tid], p1 = ptr[rowBase + tid + 1];
        sOff[tid] = p0; sCnt[tid] = p1 - p0; sInv[tid] = 1.0f / (float)(p1 - p0);
    }
    __syncthreads();
    for (int u = tid; u < BM * 10; u += 256) {
        const int r = u / 10, j = u - r * 10;
        sIdx[u] = (j < sCnt[r]) ? idx[sOff[r] + j] : 0;
    }
    __syncthreads();

    // ---- stage [agg | self] rows as bf16 ----
    for (int u = tid; u < BM * CA; u += 256) {
        const int r = u / CA, c = (u - (u / CA) * CA) * 8;
        const int row = rowBase + r;
        const int cnt = sCnt[r];
        float acc[8];
        #pragma unroll
        for (int q = 0; q < 8; ++q) acc[q] = 0.f;
        if (__builtin_expect(cnt == 10, 1)) {
            int nb[10];
            #pragma unroll
            for (int j = 0; j < 10; ++j) nb[j] = sIdx[r * 10 + j];
            short8 v[10];
            #pragma unroll
            for (int j = 0; j < 10; ++j) v[j] = *(const short8*)(src + (size_t)nb[j] * K + c);
            #pragma unroll
            for (int j = 0; j < 10; ++j)
                #pragma unroll
                for (int q = 0; q < 8; ++q) acc[q] += bf2f((unsigned short)v[j][q]);
        } else {
            for (int p = 0; p < cnt; ++p) {
                const int nb = idx[sOff[r] + p];
                const short8 v = *(const short8*)(src + (size_t)nb * K + c);
                #pragma unroll
                for (int q = 0; q < 8; ++q) acc[q] += bf2f((unsigned short)v[q]);
            }
        }
        const float inv = sInv[r];
        short8 o;
        #pragma unroll
        for (int q = 0; q < 8; ++q) o[q] = (short)f2bf(acc[q] * inv);
        *(short8*)(&sA[r * KP + c]) = o;
        *(short8*)(&sA[r * KP + K + c]) = *(const short8*)(src + (size_t)row * K + c);
    }
    __syncthreads();

    const int lane = tid & 63, wid = tid >> 6;
    const int mrow = lane & 15, kg = (lane >> 4) * 8;

    if constexpr (MODE == 0) {
        f32x4 acc[4][4];
        #pragma unroll
        for (int i = 0; i < 4; ++i)
            #pragma unroll
            for (int t = 0; t < 4; ++t) acc[i][t] = (f32x4){0.f, 0.f, 0.f, 0.f};
        const int nt0 = wid * 4;                      // 16-col tile base
        #pragma unroll
        for (int ks = 0; ks < K32; ++ks) {
            short8 aa[4];
            #pragma unroll
            for (int i = 0; i < 4; ++i)
                aa[i] = *(const short8*)(&sA[(i * 16 + mrow) * KP + ks * 32 + kg]);
            #pragma unroll
            for (int t = 0; t < 4; ++t) {
                const short8 b = *(const short8*)(Bf + ((size_t)(nt0 + t) * K32 + ks) * 512 + lane * 8);
                #pragma unroll
                for (int i = 0; i < 4; ++i)
                    acc[i][t] = __builtin_amdgcn_mfma_f32_16x16x32_bf16(aa[i], b, acc[i][t], 0, 0, 0);
            }
        }
        #pragma unroll
        for (int t = 0; t < 4; ++t) {
            const int col = (nt0 + t) * 16 + mrow;
            const float sc = gam[col] * rsqrtf(rvar[col] + BN_EPS);
            const float sh = bet[col] - rmean[col] * sc;
            const float bb = bias[col];
            #pragma unroll
            for (int i = 0; i < 4; ++i)
                #pragma unroll
                for (int reg = 0; reg < 4; ++reg) {
                    const int row = rowBase + i * 16 + (lane >> 4) * 4 + reg;
                    float h = acc[i][t][reg] + bb;
                    h = fmaxf(h * sc + sh, 0.f);
                    dstB[(size_t)row * 256 + col] = f2bf(h);
                }
        }
    } else {
        f32x4 acc[3];
        #pragma unroll
        for (int t = 0; t < 3; ++t) acc[t] = (f32x4){0.f, 0.f, 0.f, 0.f};
        #pragma unroll
        for (int ks = 0; ks < K32; ++ks) {
            const short8 aa = *(const short8*)(&sA[(wid * 16 + mrow) * KP + ks * 32 + kg]);
            #pragma unroll
            for (int t = 0; t < 3; ++t) {
                const short8 b = *(const short8*)(Bf + ((size_t)t * K32 + ks) * 512 + lane * 8);
                acc[t] = __builtin_amdgcn_mfma_f32_16x16x32_bf16(aa, b, acc[t], 0, 0, 0);
            }
        }
        const int c0 = mrow, c1 = 16 + mrow, c2 = 32 + mrow;
        const float bb0 = bias[c0], bb1 = bias[c1];
        const float bb2 = (c2 < 47) ? bias[c2] : 0.f;
        #pragma unroll
        for (int reg = 0; reg < 4; ++reg) {
            const int grow = rowBase + wid * 16 + (lane >> 4) * 4 + reg;
            const float v0 = acc[0][reg] + bb0;
            const float v1 = acc[1][reg] + bb1;
            const float v2 = (c2 < 47) ? acc[2][reg] + bb2 : -3.0e38f;
            float mx = fmaxf(fmaxf(v0, v1), v2);
            #pragma unroll
            for (int o = 1; o < 16; o <<= 1) mx = fmaxf(mx, __shfl_xor(mx, o, 16));
            float s = expf(v0 - mx) + expf(v1 - mx) + ((c2 < 47) ? expf(v2 - mx) : 0.f);
            #pragma unroll
            for (int o = 1; o < 16; o <<= 1) s += __shfl_xor(s, o, 16);
            const float ls = mx + logf(s);
            if (grow < ROWS) {
                dstF[(size_t)grow * 47 + c0] = v0 - ls;
                dstF[(size_t)grow * 47 + c1] = v1 - ls;
                if (c2 < 47) dstF[(size_t)grow * 47 + c2] = v2 - ls;
            }
        }
    }
}

extern "C" void kernel_launch(void* const* d_in, const int* in_sizes, int n_in,
                              void* d_out, int out_size, void* d_ws, size_t ws_size,
                              hipStream_t stream)
{
    char* ws = (char*)d_ws;
    Args a;
    a.x   = (const float*)d_in[0];
    a.ptr = (const int*)d_in[1];
    a.idx = (const int*)d_in[2];
    a.W0  = (const float*)d_in[3];  a.b0 = (const float*)d_in[4];  a.R0 = (const float*)d_in[5];
    a.W1  = (const float*)d_in[6];  a.b1 = (const float*)d_in[7];  a.R1 = (const float*)d_in[8];
    a.W2  = (const float*)d_in[9];  a.b2 = (const float*)d_in[10]; a.R2 = (const float*)d_in[11];
    a.g0  = (const float*)d_in[12]; a.be0 = (const float*)d_in[13];
    a.rm0 = (const float*)d_in[14]; a.rv0 = (const float*)d_in[15];
    a.g1  = (const float*)d_in[16]; a.be1 = (const float*)d_in[17];
    a.rm1 = (const float*)d_in[18]; a.rv1 = (const float*)d_in[19];
    a.B0  = (unsigned short*)(ws);                        // 16*8*64*8*2   = 128 KB
    a.B1  = (unsigned short*)(ws + 131072);               // 16*16*64*8*2  = 256 KB
    a.B2  = (unsigned short*)(ws + 393216);               //  3*16*64*8*2  =  48 KB
    a.xb  = (unsigned short*)(ws + 442368);               // RPAD*128 bf16 = 5128192 B
    a.h0  = (unsigned short*)(ws + 5570560);              // RPAD*256 bf16 = 10256384 B
    a.h1  = (unsigned short*)(ws + 15826944);             // RPAD*256 bf16
    a.out = (float*)d_out;

    prep<<<1280, 256, 0, stream>>>(a);
    layer_kernel<128, 0><<<GRID, 256, 0, stream>>>(a.xb, a.ptr, a.idx, a.B0, a.b0,
        a.g0, a.be0, a.rm0, a.rv0, a.h0, nullptr);
    layer_kernel<256, 0><<<GRID, 256, 0, stream>>>(a.h0, a.ptr, a.idx, a.B1, a.b1,
        a.g1, a.be1, a.rm1, a.rv1, a.h1, nullptr);
    layer_kernel<256, 1><<<GRID, 256, 0, stream>>>(a.h1, a.ptr, a.idx, a.B2, a.b2,
        nullptr, nullptr, nullptr, nullptr, nullptr, a.out);
}

// Round 6
// 77.948 us; speedup vs baseline: 6.5997x; 1.0612x over previous
//
#include <hip/hip_runtime.h>
#include <cmath>

// HistorySAGE: 3 GraphSAGE layers, only the 20000 live rows computed per layer
// (idx < 20000, output rows < 20000). 4 plain launches (coop grid.sync measured
// 3.2x slower, round 4). Round 6: BM=32 (grid 625 -> ~2.4 blocks/CU for gather
// latency hiding), self rows read directly from global in MFMA fragment layout
// (no LDS staging for them -> LDS ~19KB, occupancy 4 blocks/CU).
constexpr int ROWS = 20000;
constexpr int BM   = 32;             // rows per block tile (20000 = 625*32 exact)
constexpr int GRID = ROWS / BM;      // 625 blocks
constexpr float BN_EPS = 1e-5f;

using f32x4  = __attribute__((ext_vector_type(4))) float;
using short8 = __attribute__((ext_vector_type(8))) short;

__device__ __forceinline__ float bf2f(unsigned short u) {
    unsigned int x = ((unsigned int)u) << 16;
    return __builtin_bit_cast(float, x);
}
__device__ __forceinline__ unsigned short f2bf(float f) {
    unsigned int x = __builtin_bit_cast(unsigned int, f);
    unsigned int r = x + 0x7fffu + ((x >> 16) & 1u);   // RNE
    return (unsigned short)(r >> 16);
}

// Fragment-major weight layout: Bf[((n16*K32 + k32)*64 + lane)*8 + q] =
// bf16 of Wcat[k32*32 + (lane>>4)*8 + q][n16*16 + (lane&15)], Wcat = [W; R].
// A wave reading lane*8 shorts at a (n16,k32) block base gets its exact
// 16x16x32 MFMA B-fragment fully coalesced (1KB/wave).
__device__ __forceinline__ void convw_frag(const float* __restrict__ W, const float* __restrict__ R,
                                           unsigned short* __restrict__ B, int K, int Ntrue, int N16,
                                           int gtid, int gstride)
{
    const int K32 = 2 * K / 32;
    const int total = N16 * K32 * 64;
    for (int j = gtid; j < total; j += gstride) {
        const int lane = j & 63;
        const int rest = j >> 6;
        const int k32 = rest % K32, n16 = rest / K32;
        const int n  = n16 * 16 + (lane & 15);
        const int kb = k32 * 32 + (lane >> 4) * 8;
        short8 o;
        #pragma unroll
        for (int q = 0; q < 8; ++q) {
            const int kk = kb + q;
            float v = 0.f;
            if (n < Ntrue) v = (kk < K) ? W[(size_t)kk * Ntrue + n] : R[(size_t)(kk - K) * Ntrue + n];
            o[q] = (short)f2bf(v);
        }
        *(short8*)(B + (size_t)j * 8) = o;
    }
}

struct Args {
    const float* x; const int* ptr; const int* idx;
    const float *W0, *b0, *R0, *W1, *b1, *R1, *W2, *b2, *R2;
    const float *g0, *be0, *rm0, *rv0, *g1, *be1, *rm1, *rv1;
    unsigned short *B0, *B1, *B2, *xb, *h0, *h1;
    float* out;
};

// prep: x rows [0,ROWS) -> bf16 (halves L0 gather bytes) + all weight buffers.
__global__ __launch_bounds__(256) void prep(Args a)
{
    const int gtid = blockIdx.x * 256 + threadIdx.x, gstride = gridDim.x * 256;
    for (int i = gtid; i < ROWS * 16; i += gstride) {
        const int row = i >> 4, c = (i & 15) * 8;
        const float4 v0 = *(const float4*)(a.x + (size_t)row * 128 + c);
        const float4 v1 = *(const float4*)(a.x + (size_t)row * 128 + c + 4);
        short8 o;
        o[0]=(short)f2bf(v0.x); o[1]=(short)f2bf(v0.y); o[2]=(short)f2bf(v0.z); o[3]=(short)f2bf(v0.w);
        o[4]=(short)f2bf(v1.x); o[5]=(short)f2bf(v1.y); o[6]=(short)f2bf(v1.z); o[7]=(short)f2bf(v1.w);
        *(short8*)(a.xb + (size_t)row * 128 + c) = o;
    }
    convw_frag(a.W0, a.R0, a.B0, 128, 256, 16, gtid, gstride);
    convw_frag(a.W1, a.R1, a.B1, 256, 256, 16, gtid, gstride);
    convw_frag(a.W2, a.R2, a.B2, 256,  47,  3, gtid, gstride);
}

// MODE 0: 32 rows x 256 cols, 4 waves x (2 row-frags x 4 col-frags), BN+ReLU -> bf16.
// MODE 1: 32 rows x 47 cols, waves 0,1 x (1 row-frag x 3 col-frags), log_softmax -> f32.
// A-operand: aggregated half (cols 0..K) from LDS; self half (cols K..2K) read
// directly from global in fragment layout (16B/lane) - no LDS staging.
template<int K, int MODE>
__global__ __launch_bounds__(256, 4)
void layer_kernel(const unsigned short* __restrict__ src,
                  const int* __restrict__ ptr, const int* __restrict__ idx,
                  const unsigned short* __restrict__ Bf, const float* __restrict__ bias,
                  const float* __restrict__ gam, const float* __restrict__ bet,
                  const float* __restrict__ rmean, const float* __restrict__ rvar,
                  unsigned short* __restrict__ dstB, float* __restrict__ dstF)
{
    constexpr int Kt = 2 * K, KA = K + 8, CA = K / 8;
    constexpr int KS_A = K / 32;         // aggregated-half k-steps
    constexpr int KS_T = Kt / 32;        // total k-steps (B index space)
    __shared__ unsigned short sA[BM * KA];
    __shared__ int   sIdx[BM * 10];
    __shared__ int   sOff[BM];
    __shared__ int   sCnt[BM];
    __shared__ float sInv[BM];

    const int tid = threadIdx.x;
    const int rowBase = blockIdx.x * BM;

    // ---- graph meta ----
    if (tid < BM) {
        const int p0 = ptr[rowBase + tid], p1 = ptr[rowBase + tid + 1];
        sOff[tid] = p0; sCnt[tid] = p1 - p0; sInv[tid] = 1.0f / (float)(p1 - p0);
    }
    __syncthreads();
    for (int u = tid; u < BM * 10; u += 256) {
        const int r = u / 10, j = u - r * 10;
        sIdx[u] = (j < sCnt[r]) ? idx[sOff[r] + j] : 0;
    }
    __syncthreads();

    // ---- gather: 10-neighbor mean rows -> LDS (bf16) ----
    for (int u = tid; u < BM * CA; u += 256) {
        const int r = u / CA, c = (u - (u / CA) * CA) * 8;
        const int cnt = sCnt[r];
        float acc[8];
        #pragma unroll
        for (int q = 0; q < 8; ++q) acc[q] = 0.f;
        if (__builtin_expect(cnt == 10, 1)) {
            int nb[10];
            #pragma unroll
            for (int j = 0; j < 10; ++j) nb[j] = sIdx[r * 10 + j];
            short8 v[10];
            #pragma unroll
            for (int j = 0; j < 10; ++j) v[j] = *(const short8*)(src + (size_t)nb[j] * K + c);
            #pragma unroll
            for (int j = 0; j < 10; ++j)
                #pragma unroll
                for (int q = 0; q < 8; ++q) acc[q] += bf2f((unsigned short)v[j][q]);
        } else {
            for (int p = 0; p < cnt; ++p) {
                const int nb = idx[sOff[r] + p];
                const short8 v = *(const short8*)(src + (size_t)nb * K + c);
                #pragma unroll
                for (int q = 0; q < 8; ++q) acc[q] += bf2f((unsigned short)v[q]);
            }
        }
        const float inv = sInv[r];
        short8 o;
        #pragma unroll
        for (int q = 0; q < 8; ++q) o[q] = (short)f2bf(acc[q] * inv);
        *(short8*)(&sA[r * KA + c]) = o;
    }
    __syncthreads();

    const int lane = tid & 63, wid = tid >> 6;
    const int mrow = lane & 15, kg = (lane >> 4) * 8;

    if constexpr (MODE == 0) {
        f32x4 acc[2][4];
        #pragma unroll
        for (int i = 0; i < 2; ++i)
            #pragma unroll
            for (int t = 0; t < 4; ++t) acc[i][t] = (f32x4){0.f, 0.f, 0.f, 0.f};
        const int nt0 = wid * 4;

        // self half first (global loads issue early, hide under MFMA)
        #pragma unroll
        for (int ks2 = 0; ks2 < KS_A; ++ks2) {
            const int kc = ks2 * 32 + kg;
            const short8 a0 = *(const short8*)(src + (size_t)(rowBase + mrow) * K + kc);
            const short8 a1 = *(const short8*)(src + (size_t)(rowBase + 16 + mrow) * K + kc);
            #pragma unroll
            for (int t = 0; t < 4; ++t) {
                const short8 b = *(const short8*)(Bf + ((size_t)(nt0 + t) * KS_T + KS_A + ks2) * 512 + lane * 8);
                acc[0][t] = __builtin_amdgcn_mfma_f32_16x16x32_bf16(a0, b, acc[0][t], 0, 0, 0);
                acc[1][t] = __builtin_amdgcn_mfma_f32_16x16x32_bf16(a1, b, acc[1][t], 0, 0, 0);
            }
        }
        // aggregated half from LDS
        #pragma unroll
        for (int ks = 0; ks < KS_A; ++ks) {
            const short8 a0 = *(const short8*)(&sA[mrow * KA + ks * 32 + kg]);
            const short8 a1 = *(const short8*)(&sA[(16 + mrow) * KA + ks * 32 + kg]);
            #pragma unroll
            for (int t = 0; t < 4; ++t) {
                const short8 b = *(const short8*)(Bf + ((size_t)(nt0 + t) * KS_T + ks) * 512 + lane * 8);
                acc[0][t] = __builtin_amdgcn_mfma_f32_16x16x32_bf16(a0, b, acc[0][t], 0, 0, 0);
                acc[1][t] = __builtin_amdgcn_mfma_f32_16x16x32_bf16(a1, b, acc[1][t], 0, 0, 0);
            }
        }
        #pragma unroll
        for (int t = 0; t < 4; ++t) {
            const int col = (nt0 + t) * 16 + mrow;
            const float sc = gam[col] * rsqrtf(rvar[col] + BN_EPS);
            const float sh = bet[col] - rmean[col] * sc;
            const float bb = bias[col];
            #pragma unroll
            for (int i = 0; i < 2; ++i)
                #pragma unroll
                for (int reg = 0; reg < 4; ++reg) {
                    const int row = rowBase + i * 16 + (lane >> 4) * 4 + reg;
                    float h = acc[i][t][reg] + bb;
                    h = fmaxf(h * sc + sh, 0.f);
                    dstB[(size_t)row * 256 + col] = f2bf(h);
                }
        }
    } else {
        if (wid >= 2) return;                 // last phase: no further barriers
        f32x4 acc[3];
        #pragma unroll
        for (int t = 0; t < 3; ++t) acc[t] = (f32x4){0.f, 0.f, 0.f, 0.f};
        const int arow = rowBase + wid * 16 + mrow;
        #pragma unroll
        for (int ks2 = 0; ks2 < KS_A; ++ks2) {
            const short8 aa = *(const short8*)(src + (size_t)arow * K + ks2 * 32 + kg);
            #pragma unroll
            for (int t = 0; t < 3; ++t) {
                const short8 b = *(const short8*)(Bf + ((size_t)t * KS_T + KS_A + ks2) * 512 + lane * 8);
                acc[t] = __builtin_amdgcn_mfma_f32_16x16x32_bf16(aa, b, acc[t], 0, 0, 0);
            }
        }
        #pragma unroll
        for (int ks = 0; ks < KS_A; ++ks) {
            const short8 aa = *(const short8*)(&sA[(wid * 16 + mrow) * KA + ks * 32 + kg]);
            #pragma unroll
            for (int t = 0; t < 3; ++t) {
                const short8 b = *(const short8*)(Bf + ((size_t)t * KS_T + ks) * 512 + lane * 8);
                acc[t] = __builtin_amdgcn_mfma_f32_16x16x32_bf16(aa, b, acc[t], 0, 0, 0);
            }
        }
        const int c0 = mrow, c1 = 16 + mrow, c2 = 32 + mrow;
        const float bb0 = bias[c0], bb1 = bias[c1];
        const float bb2 = (c2 < 47) ? bias[c2] : 0.f;
        #pragma unroll
        for (int reg = 0; reg < 4; ++reg) {
            const int grow = rowBase + wid * 16 + (lane >> 4) * 4 + reg;
            const float v0 = acc[0][reg] + bb0;
            const float v1 = acc[1][reg] + bb1;
            const float v2 = (c2 < 47) ? acc[2][reg] + bb2 : -3.0e38f;
            float mx = fmaxf(fmaxf(v0, v1), v2);
            #pragma unroll
            for (int o = 1; o < 16; o <<= 1) mx = fmaxf(mx, __shfl_xor(mx, o, 16));
            float s = expf(v0 - mx) + expf(v1 - mx) + ((c2 < 47) ? expf(v2 - mx) : 0.f);
            #pragma unroll
            for (int o = 1; o < 16; o <<= 1) s += __shfl_xor(s, o, 16);
            const float ls = mx + logf(s);
            dstF[(size_t)grow * 47 + c0] = v0 - ls;
            dstF[(size_t)grow * 47 + c1] = v1 - ls;
            if (c2 < 47) dstF[(size_t)grow * 47 + c2] = v2 - ls;
        }
    }
}

extern "C" void kernel_launch(void* const* d_in, const int* in_sizes, int n_in,
                              void* d_out, int out_size, void* d_ws, size_t ws_size,
                              hipStream_t stream)
{
    char* ws = (char*)d_ws;
    Args a;
    a.x   = (const float*)d_in[0];
    a.ptr = (const int*)d_in[1];
    a.idx = (const int*)d_in[2];
    a.W0  = (const float*)d_in[3];  a.b0 = (const float*)d_in[4];  a.R0 = (const float*)d_in[5];
    a.W1  = (const float*)d_in[6];  a.b1 = (const float*)d_in[7];  a.R1 = (const float*)d_in[8];
    a.W2  = (const float*)d_in[9];  a.b2 = (const float*)d_in[10]; a.R2 = (const float*)d_in[11];
    a.g0  = (const float*)d_in[12]; a.be0 = (const float*)d_in[13];
    a.rm0 = (const float*)d_in[14]; a.rv0 = (const float*)d_in[15];
    a.g1  = (const float*)d_in[16]; a.be1 = (const float*)d_in[17];
    a.rm1 = (const float*)d_in[18]; a.rv1 = (const float*)d_in[19];
    a.B0  = (unsigned short*)(ws);                        // 128 KB
    a.B1  = (unsigned short*)(ws + 131072);               // 256 KB
    a.B2  = (unsigned short*)(ws + 393216);               //  48 KB
    a.xb  = (unsigned short*)(ws + 442368);               // 20000*128 bf16 = 5.12 MB
    a.h0  = (unsigned short*)(ws + 5562368);              // 20000*256 bf16 = 10.24 MB
    a.h1  = (unsigned short*)(ws + 15802368);             // 20000*256 bf16
    a.out = (float*)d_out;

    prep<<<1280, 256, 0, stream>>>(a);
    layer_kernel<128, 0><<<GRID, 256, 0, stream>>>(a.xb, a.ptr, a.idx, a.B0, a.b0,
        a.g0, a.be0, a.rm0, a.rv0, a.h0, nullptr);
    layer_kernel<256, 0><<<GRID, 256, 0, stream>>>(a.h0, a.ptr, a.idx, a.B1, a.b1,
        a.g1, a.be1, a.rm1, a.rv1, a.h1, nullptr);
    layer_kernel<256, 1><<<GRID, 256, 0, stream>>>(a.h1, a.ptr, a.idx, a.B2, a.b2,
        nullptr, nullptr, nullptr, nullptr, nullptr, a.out);
}

// Round 7
// 67.473 us; speedup vs baseline: 7.6243x; 1.1552x over previous
//
#include <hip/hip_runtime.h>
#include <cmath>

// HistorySAGE: 3 GraphSAGE layers, only the 20000 live rows computed per layer
// (idx < 20000, output rows < 20000). 4 plain launches (coop grid.sync measured
// 3.2x slower, round 4). Round 7: block-parity phase stagger — even blocks run
// self-GEMM before the gather, odd blocks after, so GPU-wide the L3 gather
// phase overlaps the MFMA/L2 GEMM phase instead of lock-stepping.
constexpr int ROWS = 20000;
constexpr int BM   = 32;             // rows per block tile (20000 = 625*32 exact)
constexpr int GRID = ROWS / BM;      // 625 blocks
constexpr float BN_EPS = 1e-5f;

using f32x4  = __attribute__((ext_vector_type(4))) float;
using short8 = __attribute__((ext_vector_type(8))) short;

__device__ __forceinline__ float bf2f(unsigned short u) {
    unsigned int x = ((unsigned int)u) << 16;
    return __builtin_bit_cast(float, x);
}
__device__ __forceinline__ unsigned short f2bf(float f) {
    unsigned int x = __builtin_bit_cast(unsigned int, f);
    unsigned int r = x + 0x7fffu + ((x >> 16) & 1u);   // RNE
    return (unsigned short)(r >> 16);
}

// Fragment-major weight layout: Bf[((n16*K32 + k32)*64 + lane)*8 + q] =
// bf16 of Wcat[k32*32 + (lane>>4)*8 + q][n16*16 + (lane&15)], Wcat = [W; R].
// A wave reading lane*8 shorts at a (n16,k32) block base gets its exact
// 16x16x32 MFMA B-fragment fully coalesced (1KB/wave).
__device__ __forceinline__ void convw_frag(const float* __restrict__ W, const float* __restrict__ R,
                                           unsigned short* __restrict__ B, int K, int Ntrue, int N16,
                                           int gtid, int gstride)
{
    const int K32 = 2 * K / 32;
    const int total = N16 * K32 * 64;
    for (int j = gtid; j < total; j += gstride) {
        const int lane = j & 63;
        const int rest = j >> 6;
        const int k32 = rest % K32, n16 = rest / K32;
        const int n  = n16 * 16 + (lane & 15);
        const int kb = k32 * 32 + (lane >> 4) * 8;
        short8 o;
        #pragma unroll
        for (int q = 0; q < 8; ++q) {
            const int kk = kb + q;
            float v = 0.f;
            if (n < Ntrue) v = (kk < K) ? W[(size_t)kk * Ntrue + n] : R[(size_t)(kk - K) * Ntrue + n];
            o[q] = (short)f2bf(v);
        }
        *(short8*)(B + (size_t)j * 8) = o;
    }
}

struct Args {
    const float* x; const int* ptr; const int* idx;
    const float *W0, *b0, *R0, *W1, *b1, *R1, *W2, *b2, *R2;
    const float *g0, *be0, *rm0, *rv0, *g1, *be1, *rm1, *rv1;
    unsigned short *B0, *B1, *B2, *xb, *h0, *h1;
    float* out;
};

// prep: x rows [0,ROWS) -> bf16 (halves L0 gather bytes) + all weight buffers.
__global__ __launch_bounds__(256) void prep(Args a)
{
    const int gtid = blockIdx.x * 256 + threadIdx.x, gstride = gridDim.x * 256;
    for (int i = gtid; i < ROWS * 16; i += gstride) {
        const int row = i >> 4, c = (i & 15) * 8;
        const float4 v0 = *(const float4*)(a.x + (size_t)row * 128 + c);
        const float4 v1 = *(const float4*)(a.x + (size_t)row * 128 + c + 4);
        short8 o;
        o[0]=(short)f2bf(v0.x); o[1]=(short)f2bf(v0.y); o[2]=(short)f2bf(v0.z); o[3]=(short)f2bf(v0.w);
        o[4]=(short)f2bf(v1.x); o[5]=(short)f2bf(v1.y); o[6]=(short)f2bf(v1.z); o[7]=(short)f2bf(v1.w);
        *(short8*)(a.xb + (size_t)row * 128 + c) = o;
    }
    convw_frag(a.W0, a.R0, a.B0, 128, 256, 16, gtid, gstride);
    convw_frag(a.W1, a.R1, a.B1, 256, 256, 16, gtid, gstride);
    convw_frag(a.W2, a.R2, a.B2, 256,  47,  3, gtid, gstride);
}

// ---- phase helpers ----

// 10-neighbor mean rows -> LDS (bf16), cooperative across the block.
template<int K>
__device__ __forceinline__ void gather_agg(const unsigned short* __restrict__ src,
    const int* __restrict__ idx, const int* sIdx, const int* sOff, const int* sCnt,
    const float* sInv, unsigned short* sA, int tid)
{
    constexpr int KA = K + 8, CA = K / 8;
    for (int u = tid; u < BM * CA; u += 256) {
        const int r = u / CA, c = (u - (u / CA) * CA) * 8;
        const int cnt = sCnt[r];
        float acc[8];
        #pragma unroll
        for (int q = 0; q < 8; ++q) acc[q] = 0.f;
        if (__builtin_expect(cnt == 10, 1)) {
            int nb[10];
            #pragma unroll
            for (int j = 0; j < 10; ++j) nb[j] = sIdx[r * 10 + j];
            short8 v[10];
            #pragma unroll
            for (int j = 0; j < 10; ++j) v[j] = *(const short8*)(src + (size_t)nb[j] * K + c);
            #pragma unroll
            for (int j = 0; j < 10; ++j)
                #pragma unroll
                for (int q = 0; q < 8; ++q) acc[q] += bf2f((unsigned short)v[j][q]);
        } else {
            for (int p = 0; p < cnt; ++p) {
                const int nb = idx[sOff[r] + p];
                const short8 v = *(const short8*)(src + (size_t)nb * K + c);
                #pragma unroll
                for (int q = 0; q < 8; ++q) acc[q] += bf2f((unsigned short)v[q]);
            }
        }
        const float inv = sInv[r];
        short8 o;
        #pragma unroll
        for (int q = 0; q < 8; ++q) o[q] = (short)f2bf(acc[q] * inv);
        *(short8*)(&sA[r * KA + c]) = o;
    }
}

// Self-half GEMM (cols K..2K of Wcat), A read directly from global in frag layout.
template<int K>
__device__ __forceinline__ void self_gemm256(const unsigned short* __restrict__ src,
    const unsigned short* __restrict__ Bf, int rowBase, int lane, int wid, f32x4 (&acc)[2][4])
{
    constexpr int KS_A = K / 32, KS_T = 2 * K / 32;
    const int mrow = lane & 15, kg = (lane >> 4) * 8;
    const int nt0 = wid * 4;
    #pragma unroll
    for (int ks2 = 0; ks2 < KS_A; ++ks2) {
        const int kc = ks2 * 32 + kg;
        const short8 a0 = *(const short8*)(src + (size_t)(rowBase + mrow) * K + kc);
        const short8 a1 = *(const short8*)(src + (size_t)(rowBase + 16 + mrow) * K + kc);
        #pragma unroll
        for (int t = 0; t < 4; ++t) {
            const short8 b = *(const short8*)(Bf + ((size_t)(nt0 + t) * KS_T + KS_A + ks2) * 512 + lane * 8);
            acc[0][t] = __builtin_amdgcn_mfma_f32_16x16x32_bf16(a0, b, acc[0][t], 0, 0, 0);
            acc[1][t] = __builtin_amdgcn_mfma_f32_16x16x32_bf16(a1, b, acc[1][t], 0, 0, 0);
        }
    }
}

// Aggregated-half GEMM (cols 0..K), A from LDS.
template<int K>
__device__ __forceinline__ void agg_gemm256(const unsigned short* sA,
    const unsigned short* __restrict__ Bf, int lane, int wid, f32x4 (&acc)[2][4])
{
    constexpr int KA = K + 8, KS_A = K / 32, KS_T = 2 * K / 32;
    const int mrow = lane & 15, kg = (lane >> 4) * 8;
    const int nt0 = wid * 4;
    #pragma unroll
    for (int ks = 0; ks < KS_A; ++ks) {
        const short8 a0 = *(const short8*)(&sA[mrow * KA + ks * 32 + kg]);
        const short8 a1 = *(const short8*)(&sA[(16 + mrow) * KA + ks * 32 + kg]);
        #pragma unroll
        for (int t = 0; t < 4; ++t) {
            const short8 b = *(const short8*)(Bf + ((size_t)(nt0 + t) * KS_T + ks) * 512 + lane * 8);
            acc[0][t] = __builtin_amdgcn_mfma_f32_16x16x32_bf16(a0, b, acc[0][t], 0, 0, 0);
            acc[1][t] = __builtin_amdgcn_mfma_f32_16x16x32_bf16(a1, b, acc[1][t], 0, 0, 0);
        }
    }
}

template<int K>
__device__ __forceinline__ void self_gemm48(const unsigned short* __restrict__ src,
    const unsigned short* __restrict__ Bf, int rowBase, int lane, int wid, f32x4 (&acc)[3])
{
    constexpr int KS_A = K / 32, KS_T = 2 * K / 32;
    const int mrow = lane & 15, kg = (lane >> 4) * 8;
    const int arow = rowBase + wid * 16 + mrow;
    #pragma unroll
    for (int ks2 = 0; ks2 < KS_A; ++ks2) {
        const short8 aa = *(const short8*)(src + (size_t)arow * K + ks2 * 32 + kg);
        #pragma unroll
        for (int t = 0; t < 3; ++t) {
            const short8 b = *(const short8*)(Bf + ((size_t)t * KS_T + KS_A + ks2) * 512 + lane * 8);
            acc[t] = __builtin_amdgcn_mfma_f32_16x16x32_bf16(aa, b, acc[t], 0, 0, 0);
        }
    }
}

template<int K>
__device__ __forceinline__ void agg_gemm48(const unsigned short* sA,
    const unsigned short* __restrict__ Bf, int lane, int wid, f32x4 (&acc)[3])
{
    constexpr int KA = K + 8, KS_A = K / 32, KS_T = 2 * K / 32;
    const int mrow = lane & 15, kg = (lane >> 4) * 8;
    #pragma unroll
    for (int ks = 0; ks < KS_A; ++ks) {
        const short8 aa = *(const short8*)(&sA[(wid * 16 + mrow) * KA + ks * 32 + kg]);
        #pragma unroll
        for (int t = 0; t < 3; ++t) {
            const short8 b = *(const short8*)(Bf + ((size_t)t * KS_T + ks) * 512 + lane * 8);
            acc[t] = __builtin_amdgcn_mfma_f32_16x16x32_bf16(aa, b, acc[t], 0, 0, 0);
        }
    }
}

// MODE 0: 32 rows x 256 cols, BN+ReLU -> bf16. MODE 1: 32 x 47, log_softmax -> f32.
template<int K, int MODE>
__global__ __launch_bounds__(256, 3)
void layer_kernel(const unsigned short* __restrict__ src,
                  const int* __restrict__ ptr, const int* __restrict__ idx,
                  const unsigned short* __restrict__ Bf, const float* __restrict__ bias,
                  const float* __restrict__ gam, const float* __restrict__ bet,
                  const float* __restrict__ rmean, const float* __restrict__ rvar,
                  unsigned short* __restrict__ dstB, float* __restrict__ dstF)
{
    constexpr int KA = K + 8;
    __shared__ unsigned short sA[BM * KA];
    __shared__ int   sIdx[BM * 10];
    __shared__ int   sOff[BM];
    __shared__ int   sCnt[BM];
    __shared__ float sInv[BM];

    const int tid = threadIdx.x;
    const int rowBase = blockIdx.x * BM;
    const bool evenBlk = (blockIdx.x & 1) == 0;   // block-uniform

    // ---- graph meta ----
    if (tid < BM) {
        const int p0 = ptr[rowBase + tid], p1 = ptr[rowBase + tid + 1];
        sOff[tid] = p0; sCnt[tid] = p1 - p0; sInv[tid] = 1.0f / (float)(p1 - p0);
    }
    __syncthreads();
    for (int u = tid; u < BM * 10; u += 256) {
        const int r = u / 10, j = u - r * 10;
        sIdx[u] = (j < sCnt[r]) ? idx[sOff[r] + j] : 0;
    }
    __syncthreads();

    const int lane = tid & 63, wid = tid >> 6;

    if constexpr (MODE == 0) {
        f32x4 acc[2][4];
        #pragma unroll
        for (int i = 0; i < 2; ++i)
            #pragma unroll
            for (int t = 0; t < 4; ++t) acc[i][t] = (f32x4){0.f, 0.f, 0.f, 0.f};

        if (evenBlk) {
            self_gemm256<K>(src, Bf, rowBase, lane, wid, acc);
            gather_agg<K>(src, idx, sIdx, sOff, sCnt, sInv, sA, tid);
            __syncthreads();
            agg_gemm256<K>(sA, Bf, lane, wid, acc);
        } else {
            gather_agg<K>(src, idx, sIdx, sOff, sCnt, sInv, sA, tid);
            __syncthreads();
            self_gemm256<K>(src, Bf, rowBase, lane, wid, acc);
            agg_gemm256<K>(sA, Bf, lane, wid, acc);
        }

        const int nt0 = wid * 4, mrow = lane & 15;
        #pragma unroll
        for (int t = 0; t < 4; ++t) {
            const int col = (nt0 + t) * 16 + mrow;
            const float sc = gam[col] * rsqrtf(rvar[col] + BN_EPS);
            const float sh = bet[col] - rmean[col] * sc;
            const float bb = bias[col];
            #pragma unroll
            for (int i = 0; i < 2; ++i)
                #pragma unroll
                for (int reg = 0; reg < 4; ++reg) {
                    const int row = rowBase + i * 16 + (lane >> 4) * 4 + reg;
                    float h = acc[i][t][reg] + bb;
                    h = fmaxf(h * sc + sh, 0.f);
                    dstB[(size_t)row * 256 + col] = f2bf(h);
                }
        }
    } else {
        f32x4 acc[3];
        #pragma unroll
        for (int t = 0; t < 3; ++t) acc[t] = (f32x4){0.f, 0.f, 0.f, 0.f};

        if (evenBlk) {
            if (wid < 2) self_gemm48<K>(src, Bf, rowBase, lane, wid, acc);
            gather_agg<K>(src, idx, sIdx, sOff, sCnt, sInv, sA, tid);
            __syncthreads();
            if (wid >= 2) return;
            agg_gemm48<K>(sA, Bf, lane, wid, acc);
        } else {
            gather_agg<K>(src, idx, sIdx, sOff, sCnt, sInv, sA, tid);
            __syncthreads();
            if (wid >= 2) return;
            self_gemm48<K>(src, Bf, rowBase, lane, wid, acc);
            agg_gemm48<K>(sA, Bf, lane, wid, acc);
        }

        const int mrow = lane & 15;
        const int c0 = mrow, c1 = 16 + mrow, c2 = 32 + mrow;
        const float bb0 = bias[c0], bb1 = bias[c1];
        const float bb2 = (c2 < 47) ? bias[c2] : 0.f;
        #pragma unroll
        for (int reg = 0; reg < 4; ++reg) {
            const int grow = rowBase + wid * 16 + (lane >> 4) * 4 + reg;
            const float v0 = acc[0][reg] + bb0;
            const float v1 = acc[1][reg] + bb1;
            const float v2 = (c2 < 47) ? acc[2][reg] + bb2 : -3.0e38f;
            float mx = fmaxf(fmaxf(v0, v1), v2);
            #pragma unroll
            for (int o = 1; o < 16; o <<= 1) mx = fmaxf(mx, __shfl_xor(mx, o, 16));
            float s = expf(v0 - mx) + expf(v1 - mx) + ((c2 < 47) ? expf(v2 - mx) : 0.f);
            #pragma unroll
            for (int o = 1; o < 16; o <<= 1) s += __shfl_xor(s, o, 16);
            const float ls = mx + logf(s);
            dstF[(size_t)grow * 47 + c0] = v0 - ls;
            dstF[(size_t)grow * 47 + c1] = v1 - ls;
            if (c2 < 47) dstF[(size_t)grow * 47 + c2] = v2 - ls;
        }
    }
}

extern "C" void kernel_launch(void* const* d_in, const int* in_sizes, int n_in,
                              void* d_out, int out_size, void* d_ws, size_t ws_size,
                              hipStream_t stream)
{
    char* ws = (char*)d_ws;
    Args a;
    a.x   = (const float*)d_in[0];
    a.ptr = (const int*)d_in[1];
    a.idx = (const int*)d_in[2];
    a.W0  = (const float*)d_in[3];  a.b0 = (const float*)d_in[4];  a.R0 = (const float*)d_in[5];
    a.W1  = (const float*)d_in[6];  a.b1 = (const float*)d_in[7];  a.R1 = (const float*)d_in[8];
    a.W2  = (const float*)d_in[9];  a.b2 = (const float*)d_in[10]; a.R2 = (const float*)d_in[11];
    a.g0  = (const float*)d_in[12]; a.be0 = (const float*)d_in[13];
    a.rm0 = (const float*)d_in[14]; a.rv0 = (const float*)d_in[15];
    a.g1  = (const float*)d_in[16]; a.be1 = (const float*)d_in[17];
    a.rm1 = (const float*)d_in[18]; a.rv1 = (const float*)d_in[19];
    a.B0  = (unsigned short*)(ws);                        // 128 KB
    a.B1  = (unsigned short*)(ws + 131072);               // 256 KB
    a.B2  = (unsigned short*)(ws + 393216);               //  48 KB
    a.xb  = (unsigned short*)(ws + 442368);               // 20000*128 bf16 = 5.12 MB
    a.h0  = (unsigned short*)(ws + 5562368);              // 20000*256 bf16 = 10.24 MB
    a.h1  = (unsigned short*)(ws + 15802368);             // 20000*256 bf16
    a.out = (float*)d_out;

    prep<<<1280, 256, 0, stream>>>(a);
    layer_kernel<128, 0><<<GRID, 256, 0, stream>>>(a.xb, a.ptr, a.idx, a.B0, a.b0,
        a.g0, a.be0, a.rm0, a.rv0, a.h0, nullptr);
    layer_kernel<256, 0><<<GRID, 256, 0, stream>>>(a.h0, a.ptr, a.idx, a.B1, a.b1,
        a.g1, a.be1, a.rm1, a.rv1, a.h1, nullptr);
    layer_kernel<256, 1><<<GRID, 256, 0, stream>>>(a.h1, a.ptr, a.idx, a.B2, a.b2,
        nullptr, nullptr, nullptr, nullptr, nullptr, a.out);
}